// Round 1
// 520.490 us; speedup vs baseline: 1.0118x; 1.0118x over previous
//
#include <hip/hip_runtime.h>

// BoxModelTriples: M=8, B=200000, D=32, N=100000
// box_param: (M, B, 2, D) float32   (51.2 MB per m-slice, 409.6 MB total)
// weights:   (M,)          float32
// ids:       (N, 4)        int32
// out:       (N,)          float32
//
// Two-pass m-phase decomposition:
//   Pass 1: grid.y = m (8 phases, x-fastest dispatch => phases time-separate).
//           Active box working set per phase = one 51.2 MB m-slice -> fully
//           L3-resident (256 MB IF cache), so repeat gathers hit L3 not HBM.
//           Wave layout: 8 rows x 8 t-lanes (d = 4t..4t+3 via float4).
//           Softmax weight computed per-lane from uniform wts (no shuffles).
//           Only cross-lane op: 3-step t-butterfly product (stays in 8-lane
//           group; offsets 1,2,4). Writes w*pA, w*pAB, w*pABC partials to ws.
//   Pass 2: per-row serial m-sum of partials (24 coalesced plane loads),
//           mask select, write out. ~13 MB traffic total.

#define MM 8
#define BB 200000
#define DD 32

__global__ __launch_bounds__(256) void box_triples_pass1(
    const float* __restrict__ box,   // (M,B,2,D)
    const float* __restrict__ wts,   // (M,)
    const int*   __restrict__ ids,   // (N,4) int32
    float*       __restrict__ ws,    // (M,3,N) weighted partial volumes
    int N)
{
    const int lane = threadIdx.x & 63;
    const int wave = threadIdx.x >> 6;
    const int m = blockIdx.y;            // one mixture component per phase
    const int r = lane >> 3;             // row within wave, 0..7
    const int t = lane & 7;              // d-chunk, d = 4t..4t+3
    const int n = (blockIdx.x * 4 + wave) * 8 + r;
    if (n >= N) return;                  // uniform per 8-lane t-group

    // ids for this row: 8 consecutive int4 per wave = one 128 B line
    const int4 idv = ((const int4*)ids)[n];
    const int i0 = idv.x, i1 = idv.y, i2 = idv.z;

    // gather: 6 independent dwordx4 loads, 8x128B coalesced segments each
    const int baseA = (m * BB + i0) * (2 * DD) + t * 4;
    const int baseB = (m * BB + i1) * (2 * DD) + t * 4;
    const int baseC = (m * BB + i2) * (2 * DD) + t * 4;

    const float4 zA4 = *(const float4*)(box + baseA);
    const float4 ZA4 = *(const float4*)(box + baseA + DD);
    const float4 zB4 = *(const float4*)(box + baseB);
    const float4 ZB4 = *(const float4*)(box + baseB + DD);
    const float4 zC4 = *(const float4*)(box + baseC);
    const float4 ZC4 = *(const float4*)(box + baseC + DD);

    // softmax weight for this m, per-lane from uniform wts (scalar loads;
    // overlaps gather latency; no cross-lane ops)
    float mx = wts[0];
    #pragma unroll
    for (int k = 1; k < MM; ++k) mx = fmaxf(mx, wts[k]);
    float s = 0.f;
    #pragma unroll
    for (int k = 0; k < MM; ++k) s += __expf(wts[k] - mx);
    const float w = __expf(wts[m] - mx) / s;

    // per-lane volume contributions over this lane's 4 dims
    float pA = 1.f, pAB = 1.f, pABC = 1.f;
    #define CL(x) fminf(fmaxf((x), 0.f), 1.f)
    #define COMP(c) { \
        const float za = CL(zA4.c), Za = CL(ZA4.c); \
        const float zb = CL(zB4.c), Zb = CL(ZB4.c); \
        const float zc = CL(zC4.c), Zc = CL(ZC4.c); \
        const float zab  = fmaxf(za, zb),  Zab  = fminf(Za, Zb); \
        const float zabc = fmaxf(zab, zc), Zabc = fminf(Zab, Zc); \
        pA   *= fmaxf(Za   - za,   0.f); \
        pAB  *= fmaxf(Zab  - zab,  0.f); \
        pABC *= fmaxf(Zabc - zabc, 0.f); \
    }
    COMP(x) COMP(y) COMP(z) COMP(w)
    #undef COMP
    #undef CL

    // product over t (8-lane group; offsets 1,2,4 stay inside the group)
    #pragma unroll
    for (int off = 1; off < 8; off <<= 1) {
        pA   *= __shfl_xor(pA,   off);
        pAB  *= __shfl_xor(pAB,  off);
        pABC *= __shfl_xor(pABC, off);
    }

    // 3 partials per row; lanes t=0,1,2 each store one plane
    if (t < 3) {
        const float v = (t == 0) ? w * pA : (t == 1) ? w * pAB : w * pABC;
        ws[(m * 3 + t) * N + n] = v;
    }
}

__global__ __launch_bounds__(256) void box_triples_pass2(
    const int*   __restrict__ ids,   // (N,4)
    const float* __restrict__ ws,    // (M,3,N)
    float*       __restrict__ out,   // (N,)
    int N)
{
    const int n = blockIdx.x * 256 + threadIdx.x;
    if (n >= N) return;

    float sA = 0.f, sAB = 0.f, sABC = 0.f;
    #pragma unroll
    for (int m = 0; m < MM; ++m) {
        sA   += ws[(m * 3 + 0) * N + n];
        sAB  += ws[(m * 3 + 1) * N + n];
        sABC += ws[(m * 3 + 2) * N + n];
    }

    const int4 idv = ((const int4*)ids)[n];
    const int i0 = idv.x, i1 = idv.y, i2 = idv.z;

    const float TINY = 1.1754943508222875e-38f;
    float res;
    if (i1 != i2) {
        res = (sABC + TINY) / (sAB + TINY);      // three_cond
    } else if (i0 != i1) {
        res = (sAB + TINY) / (sA + TINY);        // two_cond
    } else {
        res = sA;                                 // unary (universe_vol = 1)
    }
    out[n] = res;
}

// ---- fallback: previous verified single-kernel path (used if ws too small) ----
__global__ __launch_bounds__(256) void box_triples_kernel(
    const float* __restrict__ box,
    const float* __restrict__ wts,
    const int*   __restrict__ ids,
    float*       __restrict__ out,
    int N)
{
    const int lane = threadIdx.x & 63;
    const int wave = threadIdx.x >> 6;
    const int n = blockIdx.x * (blockDim.x >> 6) + wave;
    if (n >= N) return;

    const int m = lane >> 3;
    const int t = lane & 7;

    const int4 idv = ((const int4*)ids)[n];
    const int i0 = idv.x, i1 = idv.y, i2 = idv.z;

    const int baseA = (m * BB + i0) * (2 * DD) + t * 4;
    const int baseB = (m * BB + i1) * (2 * DD) + t * 4;
    const int baseC = (m * BB + i2) * (2 * DD) + t * 4;

    const float4 zA4 = *(const float4*)(box + baseA);
    const float4 ZA4 = *(const float4*)(box + baseA + DD);
    const float4 zB4 = *(const float4*)(box + baseB);
    const float4 ZB4 = *(const float4*)(box + baseB + DD);
    const float4 zC4 = *(const float4*)(box + baseC);
    const float4 ZC4 = *(const float4*)(box + baseC + DD);

    float wl = wts[m];
    float wmax = wl;
    #pragma unroll
    for (int off = 8; off < 64; off <<= 1) wmax = fmaxf(wmax, __shfl_xor(wmax, off));
    float ew = __expf(wl - wmax);
    float esum = ew;
    #pragma unroll
    for (int off = 8; off < 64; off <<= 1) esum += __shfl_xor(esum, off);
    const float w = ew / esum;

    float pA = 1.f, pAB = 1.f, pABC = 1.f;
    #define CL(x) fminf(fmaxf((x), 0.f), 1.f)
    #define COMP(c) { \
        const float za = CL(zA4.c), Za = CL(ZA4.c); \
        const float zb = CL(zB4.c), Zb = CL(ZB4.c); \
        const float zc = CL(zC4.c), Zc = CL(ZC4.c); \
        const float zab  = fmaxf(za, zb),  Zab  = fminf(Za, Zb); \
        const float zabc = fmaxf(zab, zc), Zabc = fminf(Zab, Zc); \
        pA   *= fmaxf(Za   - za,   0.f); \
        pAB  *= fmaxf(Zab  - zab,  0.f); \
        pABC *= fmaxf(Zabc - zabc, 0.f); \
    }
    COMP(x) COMP(y) COMP(z) COMP(w)
    #undef COMP
    #undef CL

    #pragma unroll
    for (int off = 1; off < 8; off <<= 1) {
        pA   *= __shfl_xor(pA,   off);
        pAB  *= __shfl_xor(pAB,  off);
        pABC *= __shfl_xor(pABC, off);
    }

    float sA = w * pA, sAB = w * pAB, sABC = w * pABC;
    #pragma unroll
    for (int off = 8; off < 64; off <<= 1) {
        sA   += __shfl_xor(sA,   off);
        sAB  += __shfl_xor(sAB,  off);
        sABC += __shfl_xor(sABC, off);
    }

    const float TINY = 1.1754943508222875e-38f;
    float res;
    if (i1 != i2) {
        res = (sABC + TINY) / (sAB + TINY);
    } else if (i0 != i1) {
        res = (sAB + TINY) / (sA + TINY);
    } else {
        res = sA;
    }

    if (lane == 0) out[n] = res;
}

extern "C" void kernel_launch(void* const* d_in, const int* in_sizes, int n_in,
                              void* d_out, int out_size, void* d_ws, size_t ws_size,
                              hipStream_t stream) {
    const float* box = (const float*)d_in[0];
    const float* wts = (const float*)d_in[1];
    const int*   ids = (const int*)d_in[2];
    float* out = (float*)d_out;
    const int N = out_size;                 // 100000

    const size_t ws_needed = (size_t)MM * 3 * N * sizeof(float);  // 9.6 MB
    if (ws_size >= ws_needed) {
        float* ws = (float*)d_ws;
        dim3 grid1((N + 31) / 32, MM);      // 32 rows/block, 8 m-phases
        box_triples_pass1<<<grid1, 256, 0, stream>>>(box, wts, ids, ws, N);
        const int blocks2 = (N + 255) / 256;
        box_triples_pass2<<<blocks2, 256, 0, stream>>>(ids, ws, out, N);
    } else {
        const int wavesPerBlock = 4;
        const int blocks = (N + wavesPerBlock - 1) / wavesPerBlock;
        box_triples_kernel<<<blocks, 256, 0, stream>>>(box, wts, ids, out, N);
    }
}

// Round 2
// 518.692 us; speedup vs baseline: 1.0153x; 1.0035x over previous
//
#include <hip/hip_runtime.h>

// BoxModelTriples: M=8, B=200000, D=32, N=100000
// box_param: (M, B, 2, D) float32   (51.2 MB per m-slice, 409.6 MB total)
// weights:   (M,)          float32
// ids:       (N, 4)        int32
// out:       (N,)          float32
//
// Fully fused single kernel. One wave = 8 rows (r = lane>>3) x 8 t-lanes
// (d = 4t..4t+3 via float4). Serial m-loop with register accumulation:
//   - All waves sweep m=0..7 in order => concurrent waves stay within ~1-2
//     m-slices (<=102 MB active working set, L3-resident) -- same phase
//     locality as the previous grid.y=m two-pass version, without the
//     second launch, the ws round-trip (9.6 MB x2), or 8x ids re-reads.
//   - Softmax max/denominator computed once per lane (scalar wts loads);
//     per-m weight recomputed inside the loop as __expf(wts[m]-mx)*inv_s
//     to avoid a runtime-indexed register array (scratch hazard).
//   - Only cross-lane ops: 3-step t-butterfly product per m (offsets 1,2,4
//     stay inside the 8-lane group). 9 shuffles per row per m.
//   - Lane t==0 of each group finalizes (mask select + divisions) and
//     stores out[n]; 8 consecutive 4B stores per wave = one 32B segment.

#define MM 8
#define BB 200000
#define DD 32

__global__ __launch_bounds__(256) void box_triples_fused(
    const float* __restrict__ box,   // (M,B,2,D)
    const float* __restrict__ wts,   // (M,)
    const int*   __restrict__ ids,   // (N,4) int32
    float*       __restrict__ out,   // (N,)
    int N)
{
    const int lane = threadIdx.x & 63;
    const int wave = threadIdx.x >> 6;
    const int r = lane >> 3;             // row within wave, 0..7
    const int t = lane & 7;              // d-chunk, d = 4t..4t+3
    const int n = (blockIdx.x * 4 + wave) * 8 + r;
    if (n >= N) return;                  // uniform within each 8-lane group

    // ids: one int4 per row; 8 distinct 16B addrs per wave (one 128B line)
    const int4 idv = ((const int4*)ids)[n];
    const int i0 = idv.x, i1 = idv.y, i2 = idv.z;

    // softmax normalizers, once per lane (wave-uniform scalar loads)
    float mx = wts[0];
    #pragma unroll
    for (int k = 1; k < MM; ++k) mx = fmaxf(mx, wts[k]);
    float s = 0.f;
    #pragma unroll
    for (int k = 0; k < MM; ++k) s += __expf(wts[k] - mx);
    const float inv_s = 1.f / s;

    // m=0 base pointers for this lane's 16B chunk of each box
    const float* pa = box + i0 * (2 * DD) + t * 4;
    const float* pb = box + i1 * (2 * DD) + t * 4;
    const float* pc = box + i2 * (2 * DD) + t * 4;

    float sA = 0.f, sAB = 0.f, sABC = 0.f;

    #pragma unroll 2
    for (int m = 0; m < MM; ++m) {
        const size_t moff = (size_t)m * (BB * 2 * DD);

        const float4 zA4 = *(const float4*)(pa + moff);
        const float4 ZA4 = *(const float4*)(pa + moff + DD);
        const float4 zB4 = *(const float4*)(pb + moff);
        const float4 ZB4 = *(const float4*)(pb + moff + DD);
        const float4 zC4 = *(const float4*)(pc + moff);
        const float4 ZC4 = *(const float4*)(pc + moff + DD);

        // per-m weight recomputed (no runtime-indexed array -> no scratch)
        const float w = __expf(wts[m] - mx) * inv_s;

        float pA = 1.f, pAB = 1.f, pABC = 1.f;
        #define CL(x) fminf(fmaxf((x), 0.f), 1.f)
        #define COMP(c) { \
            const float za = CL(zA4.c), Za = CL(ZA4.c); \
            const float zb = CL(zB4.c), Zb = CL(ZB4.c); \
            const float zc = CL(zC4.c), Zc = CL(ZC4.c); \
            const float zab  = fmaxf(za, zb),  Zab  = fminf(Za, Zb); \
            const float zabc = fmaxf(zab, zc), Zabc = fminf(Zab, Zc); \
            pA   *= fmaxf(Za   - za,   0.f); \
            pAB  *= fmaxf(Zab  - zab,  0.f); \
            pABC *= fmaxf(Zabc - zabc, 0.f); \
        }
        COMP(x) COMP(y) COMP(z) COMP(w)
        #undef COMP
        #undef CL

        // product over t (8-lane group; offsets 1,2,4 stay inside group)
        #pragma unroll
        for (int off = 1; off < 8; off <<= 1) {
            pA   *= __shfl_xor(pA,   off);
            pAB  *= __shfl_xor(pAB,  off);
            pABC *= __shfl_xor(pABC, off);
        }

        sA   += w * pA;
        sAB  += w * pAB;
        sABC += w * pABC;
    }

    const float TINY = 1.1754943508222875e-38f;
    float res;
    if (i1 != i2) {
        res = (sABC + TINY) / (sAB + TINY);      // three_cond
    } else if (i0 != i1) {
        res = (sAB + TINY) / (sA + TINY);        // two_cond
    } else {
        res = sA;                                 // unary (universe_vol = 1)
    }

    if (t == 0) out[n] = res;
}

extern "C" void kernel_launch(void* const* d_in, const int* in_sizes, int n_in,
                              void* d_out, int out_size, void* d_ws, size_t ws_size,
                              hipStream_t stream) {
    const float* box = (const float*)d_in[0];
    const float* wts = (const float*)d_in[1];
    const int*   ids = (const int*)d_in[2];
    float* out = (float*)d_out;
    const int N = out_size;                 // 100000

    // 32 rows per block (4 waves x 8 rows)
    const int blocks = (N + 31) / 32;
    box_triples_fused<<<blocks, 256, 0, stream>>>(box, wts, ids, out, N);
}